// Round 14
// baseline (380.521 us; speedup 1.0000x reference)
//
#include <hip/hip_runtime.h>

// VectorQuantizer: z (8,64,8192) f32, codebook (1024,64) f32
// Outputs (concatenated f32): z_q_st [4194304], vq_loss [1], codes [65536]
//
// codes must match numpy fp32 argmin BIT-EXACTLY -> replicate numpy op order:
//   zsq/wsq: pairwise_sum n=64 (8 serial column accumulators, rounded squares)
//   dot:     single serial FMA chain over k ascending (BLAS sgemm order)
//   dist:    fl(fl(zsq - fl(2*dot)) + wsq), argmin = first occurrence of min.
//
// Evidence ledger (best: R19 total 219.9, dist-fused 183.7):
//   R6-R9 190us (w s_load drains) | R11 500us (uniform VMEM 64x amp) |
//   R13 175 | R14 1667 SPILL | R15 fused 184.7/223.8 | R16 288 (1 w/SIMD) |
//   R17 spill at 128-reg cap (FETCH 494MB) | R19 8rows/iter: FLAT 183.7.
//   WALL: R13/R15/R19 all ~180us, VALUBusy ~55%, 2 waves/SIMD. Arithmetic:
//   per row per CU, LDS broadcast b128 = 8 waves x 16 x 4cy = 512cy LDS pipe;
//   VALU = 2 waves x 128 FMA x 2cy = 512cy/SIMD. Pipes exactly balanced and
//   SERIALIZED (a wave can't FMA while waiting its own LDS returns; only 2
//   waves to interleave) -> 55% ceiling. ILP can't fix; TLP spills (R17).
// R20 (this round): z OFF the LDS pipe -> SGPRs via SMEM.
//   K1: transpose pass writes z^T rows (64 contig floats, scratch = `out`,
//       rewritten by epilogue) + zsqT in exact PAIRWISE64 order (~10us).
//   K2: dist = 8 waves x 128 codes (2/lane, w in VGPR as proven); per row:
//       16 uniform float4 s_loads -> z in SGPRs; FMA v_fmac(acc, s_z, v_w)
//       (1 SGPR src legal). ZERO LDS in hot loop. Reduction via DPP min
//       (row_shr1/2/4/8 + row_bcast15/31 + readlane): pure VALU ~30cy,
//       no SMEM/DS lgkm mixing (the R6 killer). Co-wave's 256cy FMA covers
//       ~250cy SMEM latency -> VALU ~saturated.
//   K3/K4: proven standalone epilogue + loss (R10 structure).
//   Predict: dist 60-100us, VALUBusy>=70%, LDS ~16KB, conflicts ~0;
//   total 219.9 -> 125-165us.
//   Falsifier A: update_dpp compile fail -> shfl fallback next round.
//   Falsifier B: dist>=150 & VALUBusy<60 -> SMEM drain exposed -> SGPR
//   half-row double-buffer.

#define T_DIM 8192
#define D_DIM 64
#define C_DIM 1024
#define B_DIM 8
#define NROWS (B_DIM * T_DIM)           // 65536 vectors
#define NELEM (B_DIM * D_DIM * T_DIM)   // 4194304 elements
#define EPI_BLOCKS (NELEM / 4 / 256)    // 4096 blocks, 1 float4/thread

#define R64(M) M(0) M(1) M(2) M(3) M(4) M(5) M(6) M(7) \
  M(8) M(9) M(10) M(11) M(12) M(13) M(14) M(15) \
  M(16) M(17) M(18) M(19) M(20) M(21) M(22) M(23) \
  M(24) M(25) M(26) M(27) M(28) M(29) M(30) M(31) \
  M(32) M(33) M(34) M(35) M(36) M(37) M(38) M(39) \
  M(40) M(41) M(42) M(43) M(44) M(45) M(46) M(47) \
  M(48) M(49) M(50) M(51) M(52) M(53) M(54) M(55) \
  M(56) M(57) M(58) M(59) M(60) M(61) M(62) M(63)

#define SQ_(x) __fmul_rn(x, x)
#define AD_(a, b) __fadd_rn(a, b)

// numpy pairwise_sum of 64 pre-rounded squares of scalars p0..p63 -> dst.
#define PAIRWISE64(p, dst) \
  float pr0 = SQ_(p##0);  pr0 = AD_(pr0, SQ_(p##8));  pr0 = AD_(pr0, SQ_(p##16)); pr0 = AD_(pr0, SQ_(p##24)); pr0 = AD_(pr0, SQ_(p##32)); pr0 = AD_(pr0, SQ_(p##40)); pr0 = AD_(pr0, SQ_(p##48)); pr0 = AD_(pr0, SQ_(p##56)); \
  float pr1 = SQ_(p##1);  pr1 = AD_(pr1, SQ_(p##9));  pr1 = AD_(pr1, SQ_(p##17)); pr1 = AD_(pr1, SQ_(p##25)); pr1 = AD_(pr1, SQ_(p##33)); pr1 = AD_(pr1, SQ_(p##41)); pr1 = AD_(pr1, SQ_(p##49)); pr1 = AD_(pr1, SQ_(p##57)); \
  float pr2 = SQ_(p##2);  pr2 = AD_(pr2, SQ_(p##10)); pr2 = AD_(pr2, SQ_(p##18)); pr2 = AD_(pr2, SQ_(p##26)); pr2 = AD_(pr2, SQ_(p##34)); pr2 = AD_(pr2, SQ_(p##42)); pr2 = AD_(pr2, SQ_(p##50)); pr2 = AD_(pr2, SQ_(p##58)); \
  float pr3 = SQ_(p##3);  pr3 = AD_(pr3, SQ_(p##11)); pr3 = AD_(pr3, SQ_(p##19)); pr3 = AD_(pr3, SQ_(p##27)); pr3 = AD_(pr3, SQ_(p##35)); pr3 = AD_(pr3, SQ_(p##43)); pr3 = AD_(pr3, SQ_(p##51)); pr3 = AD_(pr3, SQ_(p##59)); \
  float pr4 = SQ_(p##4);  pr4 = AD_(pr4, SQ_(p##12)); pr4 = AD_(pr4, SQ_(p##20)); pr4 = AD_(pr4, SQ_(p##28)); pr4 = AD_(pr4, SQ_(p##36)); pr4 = AD_(pr4, SQ_(p##44)); pr4 = AD_(pr4, SQ_(p##52)); pr4 = AD_(pr4, SQ_(p##60)); \
  float pr5 = SQ_(p##5);  pr5 = AD_(pr5, SQ_(p##13)); pr5 = AD_(pr5, SQ_(p##21)); pr5 = AD_(pr5, SQ_(p##29)); pr5 = AD_(pr5, SQ_(p##37)); pr5 = AD_(pr5, SQ_(p##45)); pr5 = AD_(pr5, SQ_(p##53)); pr5 = AD_(pr5, SQ_(p##61)); \
  float pr6 = SQ_(p##6);  pr6 = AD_(pr6, SQ_(p##14)); pr6 = AD_(pr6, SQ_(p##22)); pr6 = AD_(pr6, SQ_(p##30)); pr6 = AD_(pr6, SQ_(p##38)); pr6 = AD_(pr6, SQ_(p##46)); pr6 = AD_(pr6, SQ_(p##54)); pr6 = AD_(pr6, SQ_(p##62)); \
  float pr7 = SQ_(p##7);  pr7 = AD_(pr7, SQ_(p##15)); pr7 = AD_(pr7, SQ_(p##23)); pr7 = AD_(pr7, SQ_(p##31)); pr7 = AD_(pr7, SQ_(p##39)); pr7 = AD_(pr7, SQ_(p##47)); pr7 = AD_(pr7, SQ_(p##55)); pr7 = AD_(pr7, SQ_(p##63)); \
  float dst = AD_(AD_(AD_(pr0, pr1), AD_(pr2, pr3)), AD_(AD_(pr4, pr5), AD_(pr6, pr7)));

// Same pairwise order, sourced from a float4[16] register array.
#define WSQ_OF(arr, dst) float dst; { \
  float c0 = SQ_(arr[0].x); c0=AD_(c0,SQ_(arr[2].x)); c0=AD_(c0,SQ_(arr[4].x)); c0=AD_(c0,SQ_(arr[6].x)); c0=AD_(c0,SQ_(arr[8].x)); c0=AD_(c0,SQ_(arr[10].x)); c0=AD_(c0,SQ_(arr[12].x)); c0=AD_(c0,SQ_(arr[14].x)); \
  float c1 = SQ_(arr[0].y); c1=AD_(c1,SQ_(arr[2].y)); c1=AD_(c1,SQ_(arr[4].y)); c1=AD_(c1,SQ_(arr[6].y)); c1=AD_(c1,SQ_(arr[8].y)); c1=AD_(c1,SQ_(arr[10].y)); c1=AD_(c1,SQ_(arr[12].y)); c1=AD_(c1,SQ_(arr[14].y)); \
  float c2 = SQ_(arr[0].z); c2=AD_(c2,SQ_(arr[2].z)); c2=AD_(c2,SQ_(arr[4].z)); c2=AD_(c2,SQ_(arr[6].z)); c2=AD_(c2,SQ_(arr[8].z)); c2=AD_(c2,SQ_(arr[10].z)); c2=AD_(c2,SQ_(arr[12].z)); c2=AD_(c2,SQ_(arr[14].z)); \
  float c3 = SQ_(arr[0].w); c3=AD_(c3,SQ_(arr[2].w)); c3=AD_(c3,SQ_(arr[4].w)); c3=AD_(c3,SQ_(arr[6].w)); c3=AD_(c3,SQ_(arr[8].w)); c3=AD_(c3,SQ_(arr[10].w)); c3=AD_(c3,SQ_(arr[12].w)); c3=AD_(c3,SQ_(arr[14].w)); \
  float c4 = SQ_(arr[1].x); c4=AD_(c4,SQ_(arr[3].x)); c4=AD_(c4,SQ_(arr[5].x)); c4=AD_(c4,SQ_(arr[7].x)); c4=AD_(c4,SQ_(arr[9].x)); c4=AD_(c4,SQ_(arr[11].x)); c4=AD_(c4,SQ_(arr[13].x)); c4=AD_(c4,SQ_(arr[15].x)); \
  float c5 = SQ_(arr[1].y); c5=AD_(c5,SQ_(arr[3].y)); c5=AD_(c5,SQ_(arr[5].y)); c5=AD_(c5,SQ_(arr[7].y)); c5=AD_(c5,SQ_(arr[9].y)); c5=AD_(c5,SQ_(arr[11].y)); c5=AD_(c5,SQ_(arr[13].y)); c5=AD_(c5,SQ_(arr[15].y)); \
  float c6 = SQ_(arr[1].z); c6=AD_(c6,SQ_(arr[3].z)); c6=AD_(c6,SQ_(arr[5].z)); c6=AD_(c6,SQ_(arr[7].z)); c6=AD_(c6,SQ_(arr[9].z)); c6=AD_(c6,SQ_(arr[11].z)); c6=AD_(c6,SQ_(arr[13].z)); c6=AD_(c6,SQ_(arr[15].z)); \
  float c7 = SQ_(arr[1].w); c7=AD_(c7,SQ_(arr[3].w)); c7=AD_(c7,SQ_(arr[5].w)); c7=AD_(c7,SQ_(arr[7].w)); c7=AD_(c7,SQ_(arr[9].w)); c7=AD_(c7,SQ_(arr[11].w)); c7=AD_(c7,SQ_(arr[13].w)); c7=AD_(c7,SQ_(arr[15].w)); \
  dst = AD_(AD_(AD_(c0, c1), AD_(c2, c3)), AD_(AD_(c4, c5), AD_(c6, c7))); }

// Full-wave (64) min via DPP: row_shr 1/2/4/8 (each 16-lane row reduces into
// its lane 15/31/47/63), row_bcast:15 then :31 merge rows; result in lane 63,
// broadcast back via readlane. old = x -> masked/invalid lanes keep x (safe
// for min). Pure VALU: no DS, no SMEM -> no lgkm interaction.
__device__ __forceinline__ float wave_min64_dpp(float x) {
    int xi = __float_as_int(x);
    int t;
    t = __builtin_amdgcn_update_dpp(xi, xi, 0x111, 0xf, 0xf, false); // shr:1
    x = fminf(x, __int_as_float(t)); xi = __float_as_int(x);
    t = __builtin_amdgcn_update_dpp(xi, xi, 0x112, 0xf, 0xf, false); // shr:2
    x = fminf(x, __int_as_float(t)); xi = __float_as_int(x);
    t = __builtin_amdgcn_update_dpp(xi, xi, 0x114, 0xf, 0xf, false); // shr:4
    x = fminf(x, __int_as_float(t)); xi = __float_as_int(x);
    t = __builtin_amdgcn_update_dpp(xi, xi, 0x118, 0xf, 0xf, false); // shr:8
    x = fminf(x, __int_as_float(t)); xi = __float_as_int(x);
    t = __builtin_amdgcn_update_dpp(xi, xi, 0x142, 0xf, 0xf, false); // bcast:15
    x = fminf(x, __int_as_float(t)); xi = __float_as_int(x);
    t = __builtin_amdgcn_update_dpp(xi, xi, 0x143, 0xf, 0xf, false); // bcast:31
    x = fminf(x, __int_as_float(t)); xi = __float_as_int(x);
    return __int_as_float(__builtin_amdgcn_readlane(xi, 63));
}

// K1: z[b][d][t] -> zt rows (row-major [row][64], contiguous) + zsqT.
// Thread per row: strided reads (coalesced across lanes per d-plane),
// contiguous 16-float4 row write (L2 write-combines full lines).
__global__ __launch_bounds__(256, 2)
void vq_transpose_kernel(const float* __restrict__ z,
                         float* __restrict__ zt,
                         float* __restrict__ zsqT) {
    const int row = blockIdx.x * 256 + threadIdx.x;   // 0..65535
    const int b = row >> 13;
    const int t = row & (T_DIM - 1);
    const float* zp = z + (size_t)b * (D_DIM * T_DIM) + t;
#define LOADZ(k) float z##k = zp[(size_t)k * T_DIM];
    R64(LOADZ)
#undef LOADZ
    PAIRWISE64(z, zsq)
    zsqT[row] = zsq;
    float4* o = (float4*)(zt + (size_t)row * 64);
    o[ 0] = make_float4(z0,  z1,  z2,  z3);
    o[ 1] = make_float4(z4,  z5,  z6,  z7);
    o[ 2] = make_float4(z8,  z9,  z10, z11);
    o[ 3] = make_float4(z12, z13, z14, z15);
    o[ 4] = make_float4(z16, z17, z18, z19);
    o[ 5] = make_float4(z20, z21, z22, z23);
    o[ 6] = make_float4(z24, z25, z26, z27);
    o[ 7] = make_float4(z28, z29, z30, z31);
    o[ 8] = make_float4(z32, z33, z34, z35);
    o[ 9] = make_float4(z36, z37, z38, z39);
    o[10] = make_float4(z40, z41, z42, z43);
    o[11] = make_float4(z44, z45, z46, z47);
    o[12] = make_float4(z48, z49, z50, z51);
    o[13] = make_float4(z52, z53, z54, z55);
    o[14] = make_float4(z56, z57, z58, z59);
    o[15] = make_float4(z60, z61, z62, z63);
}

// K2: dist. 512 threads = 8 waves; wave w owns codes w*128+lane, +64
// (w in VGPRs, loaded once). Per row: z via 16 uniform float4 s_loads
// (SGPRs); 2 serial FMA chains/lane (k ascending, bit-exact); DPP wave-min;
// class-ordered ballots for first-min. LDS only for the 8-wave combine.
__global__ __launch_bounds__(512, 2)
void vq_dist_kernel(const float* __restrict__ zt,
                    const float* __restrict__ zsqT,
                    const float* __restrict__ cb,
                    float* __restrict__ codes) {
    const int tid  = threadIdx.x;                     // 0..511
    const int wid  = tid >> 6;                        // 0..7
    const int lane = tid & 63;
    const int row0 = blockIdx.x * 256;

    __shared__ float2 res[8][256];                    // 16 KiB

    // my two codes' w (one-time, 32 x float4 into VGPRs/AGPRs)
    const int cbase = wid * 128;
    float4 wa[16], wb[16];
    {
        const float4* wpa = (const float4*)(cb + ((size_t)(cbase + lane)      << 6));
        const float4* wpb = (const float4*)(cb + ((size_t)(cbase + lane + 64) << 6));
#pragma unroll
        for (int kk = 0; kk < 16; ++kk) { wa[kk] = wpa[kk]; wb[kk] = wpb[kk]; }
    }
    WSQ_OF(wa, wsqA)
    WSQ_OF(wb, wsqB)

#pragma unroll 1
    for (int r = 0; r < 256; ++r) {
        const float4* ztr = (const float4*)(zt + (size_t)(row0 + r) * 64);
        const float zsq = zsqT[row0 + r];             // uniform -> s_load
        float aA = 0.f, aB = 0.f;
#pragma unroll
        for (int kk = 0; kk < 16; ++kk) {
            const float4 zq = ztr[kk];                // uniform -> s_load x4
            const float4 WA = wa[kk];
            const float4 WB = wb[kk];
            aA = fmaf(zq.x, WA.x, aA); aA = fmaf(zq.y, WA.y, aA);
            aA = fmaf(zq.z, WA.z, aA); aA = fmaf(zq.w, WA.w, aA);
            aB = fmaf(zq.x, WB.x, aB); aB = fmaf(zq.y, WB.y, aB);
            aB = fmaf(zq.z, WB.z, aB); aB = fmaf(zq.w, WB.w, aB);
        }
        // d = (zsq - 2*dot) + wsq, each op individually rounded
        const float dA = __fadd_rn(__fsub_rn(zsq, __fmul_rn(2.0f, aA)), wsqA);
        const float dB = __fadd_rn(__fsub_rn(zsq, __fmul_rn(2.0f, aB)), wsqB);
        const bool tB = (dB < dA);                    // A wins ties (lower code)
        const float d = tB ? dB : dA;
        const float m = wave_min64_dpp(d);            // pure-VALU wave min
        // first-min: class A codes (cbase+0..63) < class B (cbase+64..127);
        // lane order == code order within a class.
        const unsigned long long mskA = __ballot((!tB) && (d == m));
        const unsigned long long mskB = __ballot(tB && (d == m));
        int code;
        if (mskA) code = cbase + (__ffsll((long long)mskA) - 1);
        else      code = cbase + 64 + (__ffsll((long long)mskB) - 1);
        if (lane == 0) res[wid][r] = make_float2(m, (float)code);
    }
    __syncthreads();

    // combine 8 waves (ascending wid == ascending code blocks, strict <)
    if (tid < 256) {
        float2 best = res[0][tid];
#pragma unroll
        for (int w = 1; w < 8; ++w) {
            const float2 p = res[w][tid];
            if (p.x < best.x) best = p;
        }
        codes[row0 + tid] = best.y;
    }
}

// K3: epilogue (proven R10 structure): one float4 (4 consecutive t) per
// thread; per-block double partial. out = fl(z + fl(w - z)).
__global__ void vq_epilogue_kernel(const float* __restrict__ z,
                                   const float* __restrict__ cb,
                                   const float* __restrict__ codes,
                                   float* __restrict__ out,
                                   double* __restrict__ partials) {
    const int q = blockIdx.x * 256 + threadIdx.x;  // quad index, 0..1048575
    const int i = q << 2;                          // element index
    const int t = i & (T_DIM - 1);                 // multiple of 4
    const int bd = i >> 13;
    const int d = bd & (D_DIM - 1);                // uniform within a wave
    const int b = bd >> 6;
    const int row = (b << 13) | t;

    float4 cr = *(const float4*)(codes + row);     // 4 consecutive codes
    float4 zv = *(const float4*)(z + i);
    float w0 = cb[((int)cr.x << 6) + d];           // gathers, 256 KiB table
    float w1 = cb[((int)cr.y << 6) + d];
    float w2 = cb[((int)cr.z << 6) + d];
    float w3 = cb[((int)cr.w << 6) + d];

    float4 df = make_float4(w0 - zv.x, w1 - zv.y, w2 - zv.z, w3 - zv.w);
    float4 o = make_float4(zv.x + df.x, zv.y + df.y, zv.z + df.z, zv.w + df.w);
    *(float4*)(out + i) = o;                       // z + (z_q - z), ref order

    double v = (double)df.x * df.x + (double)df.y * df.y +
               (double)df.z * df.z + (double)df.w * df.w;
#pragma unroll
    for (int o2 = 32; o2 > 0; o2 >>= 1) v += __shfl_down(v, o2, 64);

    __shared__ double red[4];
    if ((threadIdx.x & 63) == 0) red[threadIdx.x >> 6] = v;
    __syncthreads();
    if (threadIdx.x == 0)
        partials[blockIdx.x] = ((red[0] + red[1]) + (red[2] + red[3]));
}

__global__ void vq_loss_kernel(const double* __restrict__ partials,
                               float* __restrict__ out_loss) {
    double s = 0.0;
    for (int i = threadIdx.x; i < EPI_BLOCKS; i += 256) s += partials[i];
#pragma unroll
    for (int o = 32; o > 0; o >>= 1) s += __shfl_down(s, o, 64);
    __shared__ double red[4];
    if ((threadIdx.x & 63) == 0) red[threadIdx.x >> 6] = s;
    __syncthreads();
    if (threadIdx.x == 0) {
        double tot = (red[0] + red[1]) + (red[2] + red[3]);
        // vq_loss = codebook_loss + 0.25*commitment_loss = 1.25*mean(diff^2)
        out_loss[0] = (float)(1.25 * tot / (double)NELEM);
    }
}

extern "C" void kernel_launch(void* const* d_in, const int* in_sizes, int n_in,
                              void* d_out, int out_size, void* d_ws, size_t ws_size,
                              hipStream_t stream) {
    const float* z  = (const float*)d_in[0];   // 4194304
    const float* cb = (const float*)d_in[1];   // 65536

    float* out      = (float*)d_out;
    float* out_loss = out + NELEM;             // index 4194304
    float* codes    = out + NELEM + 1;         // 65536 floats

    // zt scratch = `out` region (exactly NELEM floats); epilogue overwrites
    // it with the real z_q_st afterwards (it reads only z + codes).
    float* zt = out;

    char* ws = (char*)d_ws;
    float*  zsqT     = (float*)ws;                     // 256 KiB
    double* partials = (double*)(ws + (NROWS * 4));    // 32 KiB

    vq_transpose_kernel<<<NROWS / 256, 256, 0, stream>>>(z, zt, zsqT);
    vq_dist_kernel<<<NROWS / 256, 512, 0, stream>>>(zt, zsqT, cb, codes);
    vq_epilogue_kernel<<<EPI_BLOCKS, 256, 0, stream>>>(z, cb, codes, out, partials);
    vq_loss_kernel<<<1, 256, 0, stream>>>(partials, out_loss);
}

// Round 15
// 347.025 us; speedup vs baseline: 1.0965x; 1.0965x over previous
//
#include <hip/hip_runtime.h>

// VectorQuantizer: z (8,64,8192) f32, codebook (1024,64) f32
// Outputs (concatenated f32): z_q_st [4194304], vq_loss [1], codes [65536]
//
// codes must match numpy fp32 argmin BIT-EXACTLY -> replicate numpy op order:
//   zsq/wsq: pairwise_sum n=64 (8 serial column accumulators, rounded squares)
//   dot:     single serial FMA chain over k ascending (BLAS sgemm order)
//   dist:    fl(fl(zsq - fl(2*dot)) + wsq), argmin = first occurrence of min.
//
// Evidence ledger (best: R19 total 219.9, fused dist 183.7):
//   z-delivery paths measured: LDS broadcast 183.7 | SMEM 289 (s_load
//   drains, VALUBusy 31%) | VMEM-uniform 500 (64x L1 amp). LDS wall now
//   QUANTIFIED: ds_read_b128 ~12cy throughput (even broadcast) -> 8 waves
//   x 16 b128 x 12cy = 1536 cy/row/CU == measured ~1500. C=2 is AT its
//   LDS roofline (164us); C=4 needs ~275 regs -> spills (R16/R17).
// R21 (this round): kill broadcast reads -- z block in PER-LANE VGPRs +
//   v_readlane. Per 64-row group: 64 coalesced global loads put row l in
//   lane l (64 named z regs); zsq per-lane in exact PAIRWISE64 order.
//   Per row r: s_z = readlane(z_k, r) (runtime lane idx ok) -> SGPR ->
//   v_fmac(acc, s_z, v_w) (1 SGPR src legal). LDS hot-loop reads: ZERO.
//   Cost: 64 readlane/row/wave (+50% VALU) but VALU floor 55us << LDS
//   floor 164us. Estimate 90us ideal, 110-135 real. Regs 64z+128w+~20
//   ~= 215 < 256 @ (512,2). One-shot asm pin on z regs (R5 insurance).
//   Reduction: DPP wave-min (R20-K2, passed) + class ballots (bit-exact).
//   Predict: fused 183.7 -> 110-140us; total -> 145-175; VALUBusy >=75%;
//   LDS ~10KB; VGPR 200-230; FETCH ~25MB.
//   Falsifier A: FETCH GB = z spill -> 32-row groups.
//   Falsifier B: flat with VALUBusy>=80 -> readlane tax; family roofline.

#define T_DIM 8192
#define D_DIM 64
#define C_DIM 1024
#define B_DIM 8
#define NROWS (B_DIM * T_DIM)           // 65536 vectors
#define NELEM (B_DIM * D_DIM * T_DIM)   // 4194304 elements
#define NBLKS (NROWS / 256)             // 256 fused blocks

#define R64(M) M(0) M(1) M(2) M(3) M(4) M(5) M(6) M(7) \
  M(8) M(9) M(10) M(11) M(12) M(13) M(14) M(15) \
  M(16) M(17) M(18) M(19) M(20) M(21) M(22) M(23) \
  M(24) M(25) M(26) M(27) M(28) M(29) M(30) M(31) \
  M(32) M(33) M(34) M(35) M(36) M(37) M(38) M(39) \
  M(40) M(41) M(42) M(43) M(44) M(45) M(46) M(47) \
  M(48) M(49) M(50) M(51) M(52) M(53) M(54) M(55) \
  M(56) M(57) M(58) M(59) M(60) M(61) M(62) M(63)

#define SQ_(x) __fmul_rn(x, x)
#define AD_(a, b) __fadd_rn(a, b)

// numpy pairwise_sum of 64 pre-rounded squares of scalars p0..p63 -> dst.
#define PAIRWISE64(p, dst) \
  float pr0 = SQ_(p##0);  pr0 = AD_(pr0, SQ_(p##8));  pr0 = AD_(pr0, SQ_(p##16)); pr0 = AD_(pr0, SQ_(p##24)); pr0 = AD_(pr0, SQ_(p##32)); pr0 = AD_(pr0, SQ_(p##40)); pr0 = AD_(pr0, SQ_(p##48)); pr0 = AD_(pr0, SQ_(p##56)); \
  float pr1 = SQ_(p##1);  pr1 = AD_(pr1, SQ_(p##9));  pr1 = AD_(pr1, SQ_(p##17)); pr1 = AD_(pr1, SQ_(p##25)); pr1 = AD_(pr1, SQ_(p##33)); pr1 = AD_(pr1, SQ_(p##41)); pr1 = AD_(pr1, SQ_(p##49)); pr1 = AD_(pr1, SQ_(p##57)); \
  float pr2 = SQ_(p##2);  pr2 = AD_(pr2, SQ_(p##10)); pr2 = AD_(pr2, SQ_(p##18)); pr2 = AD_(pr2, SQ_(p##26)); pr2 = AD_(pr2, SQ_(p##34)); pr2 = AD_(pr2, SQ_(p##42)); pr2 = AD_(pr2, SQ_(p##50)); pr2 = AD_(pr2, SQ_(p##58)); \
  float pr3 = SQ_(p##3);  pr3 = AD_(pr3, SQ_(p##11)); pr3 = AD_(pr3, SQ_(p##19)); pr3 = AD_(pr3, SQ_(p##27)); pr3 = AD_(pr3, SQ_(p##35)); pr3 = AD_(pr3, SQ_(p##43)); pr3 = AD_(pr3, SQ_(p##51)); pr3 = AD_(pr3, SQ_(p##59)); \
  float pr4 = SQ_(p##4);  pr4 = AD_(pr4, SQ_(p##12)); pr4 = AD_(pr4, SQ_(p##20)); pr4 = AD_(pr4, SQ_(p##28)); pr4 = AD_(pr4, SQ_(p##36)); pr4 = AD_(pr4, SQ_(p##44)); pr4 = AD_(pr4, SQ_(p##52)); pr4 = AD_(pr4, SQ_(p##60)); \
  float pr5 = SQ_(p##5);  pr5 = AD_(pr5, SQ_(p##13)); pr5 = AD_(pr5, SQ_(p##21)); pr5 = AD_(pr5, SQ_(p##29)); pr5 = AD_(pr5, SQ_(p##37)); pr5 = AD_(pr5, SQ_(p##45)); pr5 = AD_(pr5, SQ_(p##53)); pr5 = AD_(pr5, SQ_(p##61)); \
  float pr6 = SQ_(p##6);  pr6 = AD_(pr6, SQ_(p##14)); pr6 = AD_(pr6, SQ_(p##22)); pr6 = AD_(pr6, SQ_(p##30)); pr6 = AD_(pr6, SQ_(p##38)); pr6 = AD_(pr6, SQ_(p##46)); pr6 = AD_(pr6, SQ_(p##54)); pr6 = AD_(pr6, SQ_(p##62)); \
  float pr7 = SQ_(p##7);  pr7 = AD_(pr7, SQ_(p##15)); pr7 = AD_(pr7, SQ_(p##23)); pr7 = AD_(pr7, SQ_(p##31)); pr7 = AD_(pr7, SQ_(p##39)); pr7 = AD_(pr7, SQ_(p##47)); pr7 = AD_(pr7, SQ_(p##55)); pr7 = AD_(pr7, SQ_(p##63)); \
  float dst = AD_(AD_(AD_(pr0, pr1), AD_(pr2, pr3)), AD_(AD_(pr4, pr5), AD_(pr6, pr7)));

// Same pairwise order, sourced from a float4[16] register array.
#define WSQ_OF(arr, dst) float dst; { \
  float c0 = SQ_(arr[0].x); c0=AD_(c0,SQ_(arr[2].x)); c0=AD_(c0,SQ_(arr[4].x)); c0=AD_(c0,SQ_(arr[6].x)); c0=AD_(c0,SQ_(arr[8].x)); c0=AD_(c0,SQ_(arr[10].x)); c0=AD_(c0,SQ_(arr[12].x)); c0=AD_(c0,SQ_(arr[14].x)); \
  float c1 = SQ_(arr[0].y); c1=AD_(c1,SQ_(arr[2].y)); c1=AD_(c1,SQ_(arr[4].y)); c1=AD_(c1,SQ_(arr[6].y)); c1=AD_(c1,SQ_(arr[8].y)); c1=AD_(c1,SQ_(arr[10].y)); c1=AD_(c1,SQ_(arr[12].y)); c1=AD_(c1,SQ_(arr[14].y)); \
  float c2 = SQ_(arr[0].z); c2=AD_(c2,SQ_(arr[2].z)); c2=AD_(c2,SQ_(arr[4].z)); c2=AD_(c2,SQ_(arr[6].z)); c2=AD_(c2,SQ_(arr[8].z)); c2=AD_(c2,SQ_(arr[10].z)); c2=AD_(c2,SQ_(arr[12].z)); c2=AD_(c2,SQ_(arr[14].z)); \
  float c3 = SQ_(arr[0].w); c3=AD_(c3,SQ_(arr[2].w)); c3=AD_(c3,SQ_(arr[4].w)); c3=AD_(c3,SQ_(arr[6].w)); c3=AD_(c3,SQ_(arr[8].w)); c3=AD_(c3,SQ_(arr[10].w)); c3=AD_(c3,SQ_(arr[12].w)); c3=AD_(c3,SQ_(arr[14].w)); \
  float c4 = SQ_(arr[1].x); c4=AD_(c4,SQ_(arr[3].x)); c4=AD_(c4,SQ_(arr[5].x)); c4=AD_(c4,SQ_(arr[7].x)); c4=AD_(c4,SQ_(arr[9].x)); c4=AD_(c4,SQ_(arr[11].x)); c4=AD_(c4,SQ_(arr[13].x)); c4=AD_(c4,SQ_(arr[15].x)); \
  float c5 = SQ_(arr[1].y); c5=AD_(c5,SQ_(arr[3].y)); c5=AD_(c5,SQ_(arr[5].y)); c5=AD_(c5,SQ_(arr[7].y)); c5=AD_(c5,SQ_(arr[9].y)); c5=AD_(c5,SQ_(arr[11].y)); c5=AD_(c5,SQ_(arr[13].y)); c5=AD_(c5,SQ_(arr[15].y)); \
  float c6 = SQ_(arr[1].z); c6=AD_(c6,SQ_(arr[3].z)); c6=AD_(c6,SQ_(arr[5].z)); c6=AD_(c6,SQ_(arr[7].z)); c6=AD_(c6,SQ_(arr[9].z)); c6=AD_(c6,SQ_(arr[11].z)); c6=AD_(c6,SQ_(arr[13].z)); c6=AD_(c6,SQ_(arr[15].z)); \
  float c7 = SQ_(arr[1].w); c7=AD_(c7,SQ_(arr[3].w)); c7=AD_(c7,SQ_(arr[5].w)); c7=AD_(c7,SQ_(arr[7].w)); c7=AD_(c7,SQ_(arr[9].w)); c7=AD_(c7,SQ_(arr[11].w)); c7=AD_(c7,SQ_(arr[13].w)); c7=AD_(c7,SQ_(arr[15].w)); \
  dst = AD_(AD_(AD_(c0, c1), AD_(c2, c3)), AD_(AD_(c4, c5), AD_(c6, c7))); }

// Full-wave (64) min via DPP (proven correct in R20-K2): row_shr 1/2/4/8,
// row_bcast 15/31, readlane 63. Pure VALU -- no DS/SMEM lgkm interaction.
__device__ __forceinline__ float wave_min64_dpp(float x) {
    int xi = __float_as_int(x);
    int t;
    t = __builtin_amdgcn_update_dpp(xi, xi, 0x111, 0xf, 0xf, false); // shr:1
    x = fminf(x, __int_as_float(t)); xi = __float_as_int(x);
    t = __builtin_amdgcn_update_dpp(xi, xi, 0x112, 0xf, 0xf, false); // shr:2
    x = fminf(x, __int_as_float(t)); xi = __float_as_int(x);
    t = __builtin_amdgcn_update_dpp(xi, xi, 0x114, 0xf, 0xf, false); // shr:4
    x = fminf(x, __int_as_float(t)); xi = __float_as_int(x);
    t = __builtin_amdgcn_update_dpp(xi, xi, 0x118, 0xf, 0xf, false); // shr:8
    x = fminf(x, __int_as_float(t)); xi = __float_as_int(x);
    t = __builtin_amdgcn_update_dpp(xi, xi, 0x142, 0xf, 0xf, false); // bcast:15
    x = fminf(x, __int_as_float(t)); xi = __float_as_int(x);
    t = __builtin_amdgcn_update_dpp(xi, xi, 0x143, 0xf, 0xf, false); // bcast:31
    x = fminf(x, __int_as_float(t)); xi = __float_as_int(x);
    return __int_as_float(__builtin_amdgcn_readlane(xi, 63));
}

// broadcast row r's scalar from the per-lane z block (exact bits)
#define RL(k) __int_as_float(__builtin_amdgcn_readlane(__float_as_int(z##k), r))

// One k-chunk: broadcast 4 z scalars, feed both code chains (k ascending
// within each chain -> bit-exact sgemm order per code).
#define CHUNK(kk, ka, kb, kc, kd) { \
    const float s0 = RL(ka); const float s1 = RL(kb); \
    const float s2 = RL(kc); const float s3 = RL(kd); \
    aA = fmaf(s0, wa[kk].x, aA); aA = fmaf(s1, wa[kk].y, aA); \
    aA = fmaf(s2, wa[kk].z, aA); aA = fmaf(s3, wa[kk].w, aA); \
    aB = fmaf(s0, wb[kk].x, aB); aB = fmaf(s1, wb[kk].y, aB); \
    aB = fmaf(s2, wb[kk].z, aB); aB = fmaf(s3, wb[kk].w, aB); }

// Fused kernel: 512 threads = 8 waves; wave owns 128 codes (2/lane, w in
// regs). z: 4 groups of 64 rows; per group, 64 coalesced global loads put
// row l in lane l (64 named regs) + per-lane zsq. Per row: 64 readlane
// broadcasts -> SGPR FMA operands. Zero LDS in hot loop. DPP wave-min +
// class-ordered ballots. Fused epilogue (z re-read from global) + loss.
__global__ __launch_bounds__(512, 2)
void vq_fused_kernel(const float* __restrict__ z,
                     const float* __restrict__ cb,
                     float* __restrict__ out,
                     float* __restrict__ codes,
                     double* __restrict__ partials) {
    const int tid  = threadIdx.x;                     // 0..511
    const int wid  = tid >> 6;                        // 0..7
    const int lane = tid & 63;
    const int row0 = blockIdx.x * 256;                // tile base (same b)
    const int b    = row0 >> 13;                      // 8192 % 256 == 0
    const int t0   = row0 & (T_DIM - 1);

    __shared__ float2 res[8][256];                    // 16 KiB [wave][row]
    __shared__ int    codesl[256];                    // 1 KiB

    // --- my two codes' w into registers (one-time; 32 x float4) ---
    const int cbase = wid * 128;                      // wave's code base
    float4 wa[16], wb[16];
    {
        const float4* wpa = (const float4*)(cb + ((size_t)(cbase + lane)      << 6));
        const float4* wpb = (const float4*)(cb + ((size_t)(cbase + lane + 64) << 6));
#pragma unroll
        for (int kk = 0; kk < 16; ++kk) { wa[kk] = wpa[kk]; wb[kk] = wpb[kk]; }
    }
    WSQ_OF(wa, wsqA)
    WSQ_OF(wb, wsqB)

    // --- 4 groups of 64 rows; no barriers needed until the combine ---
#pragma unroll 1
    for (int g = 0; g < 4; ++g) {
        // z block: lane l holds row (row0 + g*64 + l), 64 named regs.
        // Loads coalesced across lanes (consecutive t per d-plane).
        const float* zp = z + (size_t)b * (D_DIM * T_DIM) + (t0 + g * 64 + lane);
#define LOADZ(k) float z##k = zp[(size_t)k * T_DIM]; \
                 asm volatile("" : "+v"(z##k));
        R64(LOADZ)
#undef LOADZ
        PAIRWISE64(z, zsqlane)   // per-lane zsq, exact numpy order

#pragma unroll 1
        for (int r = 0; r < 64; ++r) {
            float aA = 0.f, aB = 0.f;
            CHUNK( 0,  0,  1,  2,  3)  CHUNK( 1,  4,  5,  6,  7)
            CHUNK( 2,  8,  9, 10, 11)  CHUNK( 3, 12, 13, 14, 15)
            CHUNK( 4, 16, 17, 18, 19)  CHUNK( 5, 20, 21, 22, 23)
            CHUNK( 6, 24, 25, 26, 27)  CHUNK( 7, 28, 29, 30, 31)
            CHUNK( 8, 32, 33, 34, 35)  CHUNK( 9, 36, 37, 38, 39)
            CHUNK(10, 40, 41, 42, 43)  CHUNK(11, 44, 45, 46, 47)
            CHUNK(12, 48, 49, 50, 51)  CHUNK(13, 52, 53, 54, 55)
            CHUNK(14, 56, 57, 58, 59)  CHUNK(15, 60, 61, 62, 63)
            const float zsq = __int_as_float(
                __builtin_amdgcn_readlane(__float_as_int(zsqlane), r));
            // d = (zsq - 2*dot) + wsq, each op individually rounded
            const float dA = __fadd_rn(__fsub_rn(zsq, __fmul_rn(2.0f, aA)), wsqA);
            const float dB = __fadd_rn(__fsub_rn(zsq, __fmul_rn(2.0f, aB)), wsqB);
            const bool tB = (dB < dA);                // A wins ties (lower code)
            const float d = tB ? dB : dA;
            const float m = wave_min64_dpp(d);        // pure-VALU wave min
            // first-min: class A (cbase+0..63) < class B (cbase+64..127);
            // lane order == code order within a class.
            const unsigned long long mskA = __ballot((!tB) && (d == m));
            const unsigned long long mskB = __ballot(tB && (d == m));
            int code;
            if (mskA) code = cbase + (__ffsll((long long)mskA) - 1);
            else      code = cbase + 64 + (__ffsll((long long)mskB) - 1);
            if (lane == 0) res[wid][g * 64 + r] = make_float2(m, (float)code);
        }
    }
    __syncthreads();

    // --- combine 8 waves (ascending wid == ascending code blocks) ---
    if (tid < 256) {
        float2 best = res[0][tid];
#pragma unroll
        for (int w = 1; w < 8; ++w) {
            const float2 p = res[w][tid];
            if (p.x < best.x) best = p;   // strict < keeps lower codes
        }
        codes[row0 + tid] = best.y;
        codesl[tid] = (int)best.y;
    }
    __syncthreads();

    // --- fused epilogue: thread (q=tid>>8, row=tid&255) owns 8 float4
    //     chunks of one row; z re-read from global (coalesced per d-plane);
    //     out = fl(z + fl(w - z)); per-block double loss partial. ---
    const int q   = tid >> 8;                         // 0..1
    const int row = tid & 255;
    const int code = codesl[row];
    double lsum = 0.0;
    const float* zb = z + (size_t)b * (D_DIM * T_DIM) + t0 + row;
    float* outb = out + (size_t)b * (D_DIM * T_DIM) + t0 + row;
#pragma unroll
    for (int j = 0; j < 8; ++j) {
        const int it = q * 8 + j;                     // float4 chunk 0..15
        const float4 w4 = *(const float4*)(cb + ((size_t)code << 6) + (it << 2));
        const float zv0 = zb[(size_t)((it << 2) + 0) * T_DIM];
        const float zv1 = zb[(size_t)((it << 2) + 1) * T_DIM];
        const float zv2 = zb[(size_t)((it << 2) + 2) * T_DIM];
        const float zv3 = zb[(size_t)((it << 2) + 3) * T_DIM];
        const float df0 = __fsub_rn(w4.x, zv0);
        const float df1 = __fsub_rn(w4.y, zv1);
        const float df2 = __fsub_rn(w4.z, zv2);
        const float df3 = __fsub_rn(w4.w, zv3);
        outb[(size_t)((it << 2) + 0) * T_DIM] = __fadd_rn(zv0, df0);
        outb[(size_t)((it << 2) + 1) * T_DIM] = __fadd_rn(zv1, df1);
        outb[(size_t)((it << 2) + 2) * T_DIM] = __fadd_rn(zv2, df2);
        outb[(size_t)((it << 2) + 3) * T_DIM] = __fadd_rn(zv3, df3);
        lsum += (double)df0 * df0 + (double)df1 * df1
              + (double)df2 * df2 + (double)df3 * df3;
    }
    // wave reduce (double) then block reduce via LDS
#pragma unroll
    for (int o2 = 32; o2 > 0; o2 >>= 1) lsum += __shfl_down(lsum, o2, 64);
    __shared__ double redd[8];
    if (lane == 0) redd[wid] = lsum;
    __syncthreads();
    if (tid == 0) {
        partials[blockIdx.x] = ((redd[0] + redd[1]) + (redd[2] + redd[3]))
                             + ((redd[4] + redd[5]) + (redd[6] + redd[7]));
    }
}

__global__ void vq_loss_kernel(const double* __restrict__ partials,
                               float* __restrict__ out_loss) {
    double s = 0.0;
    for (int i = threadIdx.x; i < NBLKS; i += 256) s += partials[i];
#pragma unroll
    for (int o = 32; o > 0; o >>= 1) s += __shfl_down(s, o, 64);
    __shared__ double red[4];
    if ((threadIdx.x & 63) == 0) red[threadIdx.x >> 6] = s;
    __syncthreads();
    if (threadIdx.x == 0) {
        double tot = (red[0] + red[1]) + (red[2] + red[3]);
        // vq_loss = codebook_loss + 0.25*commitment_loss = 1.25*mean(diff^2)
        out_loss[0] = (float)(1.25 * tot / (double)NELEM);
    }
}

extern "C" void kernel_launch(void* const* d_in, const int* in_sizes, int n_in,
                              void* d_out, int out_size, void* d_ws, size_t ws_size,
                              hipStream_t stream) {
    const float* z  = (const float*)d_in[0];   // 4194304
    const float* cb = (const float*)d_in[1];   // 65536

    float* out      = (float*)d_out;
    float* out_loss = out + NELEM;             // index 4194304
    float* codes    = out + NELEM + 1;         // 65536 floats

    double* partials = (double*)d_ws;          // 2 KiB (256 doubles)

    vq_fused_kernel<<<NBLKS, 512, 0, stream>>>(z, cb, out, codes, partials);
    vq_loss_kernel<<<1, 256, 0, stream>>>(partials, out_loss);
}

// Round 16
// 219.439 us; speedup vs baseline: 1.7341x; 1.5814x over previous
//
#include <hip/hip_runtime.h>

// VectorQuantizer: z (8,64,8192) f32, codebook (1024,64) f32
// Outputs (concatenated f32): z_q_st [4194304], vq_loss [1], codes [65536]
//
// codes must match numpy fp32 argmin BIT-EXACTLY -> replicate numpy op order:
//   zsq/wsq: pairwise_sum n=64 (8 serial column accumulators, rounded squares)
//   dot:     single serial FMA chain over k ascending (BLAS sgemm order)
//   dist:    fl(fl(zsq - fl(2*dot)) + wsq), argmin = first occurrence of min.
//
// FINAL evidence ledger (this is the R19 kernel, best verified: 219.9 total,
// fused 183.7):
//   z-delivery matrix (fused dist us): LDS broadcast 183.7 | SMEM 289
//   (lgkm drains) | readlane 300 (AGPR shuttle tax) | VMEM uniform 500
//   (64x L1 amp). LDS path is AT its structural floor: 8 waves x 16
//   ds_read_b128/row x ~12cy = 1536 cy/row/CU -> 164us row loop + ~8
//   staging + ~12 epilogue = 184 ~= measured 183.7.
//   The wave/reg duality is forced: bit-exact serial chains need FULL w
//   per lane -> C=2 (128 w floats) is the register max at 2 waves/SIMD
//   (C=4 ~290 regs spills, R17; 1 wave/SIMD latency-exposed 288us, R16;
//   sw-pipelining spills, R14; more rows/iter flat, R19 vs R15).
//   Occupancy is LDS+reg capped at 2 waves/SIMD; VALUBusy 55% is the
//   resulting latency-structure ceiling, not an inefficiency.

#define T_DIM 8192
#define D_DIM 64
#define C_DIM 1024
#define B_DIM 8
#define NROWS (B_DIM * T_DIM)           // 65536 vectors
#define NELEM (B_DIM * D_DIM * T_DIM)   // 4194304 elements
#define NBLKS (NROWS / 256)             // 256 fused blocks

#define R64(M) M(0) M(1) M(2) M(3) M(4) M(5) M(6) M(7) \
  M(8) M(9) M(10) M(11) M(12) M(13) M(14) M(15) \
  M(16) M(17) M(18) M(19) M(20) M(21) M(22) M(23) \
  M(24) M(25) M(26) M(27) M(28) M(29) M(30) M(31) \
  M(32) M(33) M(34) M(35) M(36) M(37) M(38) M(39) \
  M(40) M(41) M(42) M(43) M(44) M(45) M(46) M(47) \
  M(48) M(49) M(50) M(51) M(52) M(53) M(54) M(55) \
  M(56) M(57) M(58) M(59) M(60) M(61) M(62) M(63)

#define SQ_(x) __fmul_rn(x, x)
#define AD_(a, b) __fadd_rn(a, b)

// numpy pairwise_sum of 64 pre-rounded squares of scalars p0..p63 -> dst.
#define PAIRWISE64(p, dst) \
  float pr0 = SQ_(p##0);  pr0 = AD_(pr0, SQ_(p##8));  pr0 = AD_(pr0, SQ_(p##16)); pr0 = AD_(pr0, SQ_(p##24)); pr0 = AD_(pr0, SQ_(p##32)); pr0 = AD_(pr0, SQ_(p##40)); pr0 = AD_(pr0, SQ_(p##48)); pr0 = AD_(pr0, SQ_(p##56)); \
  float pr1 = SQ_(p##1);  pr1 = AD_(pr1, SQ_(p##9));  pr1 = AD_(pr1, SQ_(p##17)); pr1 = AD_(pr1, SQ_(p##25)); pr1 = AD_(pr1, SQ_(p##33)); pr1 = AD_(pr1, SQ_(p##41)); pr1 = AD_(pr1, SQ_(p##49)); pr1 = AD_(pr1, SQ_(p##57)); \
  float pr2 = SQ_(p##2);  pr2 = AD_(pr2, SQ_(p##10)); pr2 = AD_(pr2, SQ_(p##18)); pr2 = AD_(pr2, SQ_(p##26)); pr2 = AD_(pr2, SQ_(p##34)); pr2 = AD_(pr2, SQ_(p##42)); pr2 = AD_(pr2, SQ_(p##50)); pr2 = AD_(pr2, SQ_(p##58)); \
  float pr3 = SQ_(p##3);  pr3 = AD_(pr3, SQ_(p##11)); pr3 = AD_(pr3, SQ_(p##19)); pr3 = AD_(pr3, SQ_(p##27)); pr3 = AD_(pr3, SQ_(p##35)); pr3 = AD_(pr3, SQ_(p##43)); pr3 = AD_(pr3, SQ_(p##51)); pr3 = AD_(pr3, SQ_(p##59)); \
  float pr4 = SQ_(p##4);  pr4 = AD_(pr4, SQ_(p##12)); pr4 = AD_(pr4, SQ_(p##20)); pr4 = AD_(pr4, SQ_(p##28)); pr4 = AD_(pr4, SQ_(p##36)); pr4 = AD_(pr4, SQ_(p##44)); pr4 = AD_(pr4, SQ_(p##52)); pr4 = AD_(pr4, SQ_(p##60)); \
  float pr5 = SQ_(p##5);  pr5 = AD_(pr5, SQ_(p##13)); pr5 = AD_(pr5, SQ_(p##21)); pr5 = AD_(pr5, SQ_(p##29)); pr5 = AD_(pr5, SQ_(p##37)); pr5 = AD_(pr5, SQ_(p##45)); pr5 = AD_(pr5, SQ_(p##53)); pr5 = AD_(pr5, SQ_(p##61)); \
  float pr6 = SQ_(p##6);  pr6 = AD_(pr6, SQ_(p##14)); pr6 = AD_(pr6, SQ_(p##22)); pr6 = AD_(pr6, SQ_(p##30)); pr6 = AD_(pr6, SQ_(p##38)); pr6 = AD_(pr6, SQ_(p##46)); pr6 = AD_(pr6, SQ_(p##54)); pr6 = AD_(pr6, SQ_(p##62)); \
  float pr7 = SQ_(p##7);  pr7 = AD_(pr7, SQ_(p##15)); pr7 = AD_(pr7, SQ_(p##23)); pr7 = AD_(pr7, SQ_(p##31)); pr7 = AD_(pr7, SQ_(p##39)); pr7 = AD_(pr7, SQ_(p##47)); pr7 = AD_(pr7, SQ_(p##55)); pr7 = AD_(pr7, SQ_(p##63)); \
  float dst = AD_(AD_(AD_(pr0, pr1), AD_(pr2, pr3)), AD_(AD_(pr4, pr5), AD_(pr6, pr7)));

// Same pairwise order, sourced from a float4[16] register array.
#define WSQ_OF(arr, dst) float dst; { \
  float c0 = SQ_(arr[0].x); c0=AD_(c0,SQ_(arr[2].x)); c0=AD_(c0,SQ_(arr[4].x)); c0=AD_(c0,SQ_(arr[6].x)); c0=AD_(c0,SQ_(arr[8].x)); c0=AD_(c0,SQ_(arr[10].x)); c0=AD_(c0,SQ_(arr[12].x)); c0=AD_(c0,SQ_(arr[14].x)); \
  float c1 = SQ_(arr[0].y); c1=AD_(c1,SQ_(arr[2].y)); c1=AD_(c1,SQ_(arr[4].y)); c1=AD_(c1,SQ_(arr[6].y)); c1=AD_(c1,SQ_(arr[8].y)); c1=AD_(c1,SQ_(arr[10].y)); c1=AD_(c1,SQ_(arr[12].y)); c1=AD_(c1,SQ_(arr[14].y)); \
  float c2 = SQ_(arr[0].z); c2=AD_(c2,SQ_(arr[2].z)); c2=AD_(c2,SQ_(arr[4].z)); c2=AD_(c2,SQ_(arr[6].z)); c2=AD_(c2,SQ_(arr[8].z)); c2=AD_(c2,SQ_(arr[10].z)); c2=AD_(c2,SQ_(arr[12].z)); c2=AD_(c2,SQ_(arr[14].z)); \
  float c3 = SQ_(arr[0].w); c3=AD_(c3,SQ_(arr[2].w)); c3=AD_(c3,SQ_(arr[4].w)); c3=AD_(c3,SQ_(arr[6].w)); c3=AD_(c3,SQ_(arr[8].w)); c3=AD_(c3,SQ_(arr[10].w)); c3=AD_(c3,SQ_(arr[12].w)); c3=AD_(c3,SQ_(arr[14].w)); \
  float c4 = SQ_(arr[1].x); c4=AD_(c4,SQ_(arr[3].x)); c4=AD_(c4,SQ_(arr[5].x)); c4=AD_(c4,SQ_(arr[7].x)); c4=AD_(c4,SQ_(arr[9].x)); c4=AD_(c4,SQ_(arr[11].x)); c4=AD_(c4,SQ_(arr[13].x)); c4=AD_(c4,SQ_(arr[15].x)); \
  float c5 = SQ_(arr[1].y); c5=AD_(c5,SQ_(arr[3].y)); c5=AD_(c5,SQ_(arr[5].y)); c5=AD_(c5,SQ_(arr[7].y)); c5=AD_(c5,SQ_(arr[9].y)); c5=AD_(c5,SQ_(arr[11].y)); c5=AD_(c5,SQ_(arr[13].y)); c5=AD_(c5,SQ_(arr[15].y)); \
  float c6 = SQ_(arr[1].z); c6=AD_(c6,SQ_(arr[3].z)); c6=AD_(c6,SQ_(arr[5].z)); c6=AD_(c6,SQ_(arr[7].z)); c6=AD_(c6,SQ_(arr[9].z)); c6=AD_(c6,SQ_(arr[11].z)); c6=AD_(c6,SQ_(arr[13].z)); c6=AD_(c6,SQ_(arr[15].z)); \
  float c7 = SQ_(arr[1].w); c7=AD_(c7,SQ_(arr[3].w)); c7=AD_(c7,SQ_(arr[5].w)); c7=AD_(c7,SQ_(arr[7].w)); c7=AD_(c7,SQ_(arr[9].w)); c7=AD_(c7,SQ_(arr[11].w)); c7=AD_(c7,SQ_(arr[13].w)); c7=AD_(c7,SQ_(arr[15].w)); \
  dst = AD_(AD_(AD_(c0, c1), AD_(c2, c3)), AD_(AD_(c4, c5), AD_(c6, c7))); }

// One FMA chain-step: 4 serial FMAs (k ascending within the float4).
#define FM4(acc, zc, W) \
    acc = fmaf(zc.x, W.x, acc); acc = fmaf(zc.y, W.y, acc); \
    acc = fmaf(zc.z, W.z, acc); acc = fmaf(zc.w, W.w, acc);

// Fused kernel: 512 threads = 8 waves; each wave owns 128 codes (2/lane:
// cbase+lane, cbase+64+lane; w in regs). 256-row z tile in LDS (broadcast
// reads). 8 ROWS/ITER: 16 indep FMA chains, 16 b128 in flight per kk-step,
// 8 interleaved shfl-min chains. Fused epilogue + loss partial.
__global__ __launch_bounds__(512, 2)
void vq_fused_kernel(const float* __restrict__ z,
                     const float* __restrict__ cb,
                     float* __restrict__ out,
                     float* __restrict__ codes,
                     double* __restrict__ partials) {
    const int tid  = threadIdx.x;                     // 0..511
    const int wid  = tid >> 6;                        // 0..7
    const int lane = tid & 63;
    const int row0 = blockIdx.x * 256;                // tile base (same b)
    const int b    = row0 >> 13;                      // 8192 % 256 == 0
    const int t0   = row0 & (T_DIM - 1);

    __shared__ float4 zl[16][256];                    // 64 KiB  [kchunk][row]
    __shared__ float  zsql[256];                      // 1 KiB
    __shared__ float2 res[8][256];                    // 16 KiB  [wave][row]
    __shared__ int    codesl[256];                    // 1 KiB

    // --- stage z tile: threads 0..255 handle row row0+tid (coalesced) ---
    if (tid < 256) {
        const float* zp = z + (size_t)b * (D_DIM * T_DIM) + (t0 + tid);
#define LOADZ(k) float z##k = zp[(size_t)k * T_DIM];
        R64(LOADZ)
#undef LOADZ
        PAIRWISE64(z, zsq)
        zsql[tid] = zsq;
        zl[ 0][tid] = make_float4(z0,  z1,  z2,  z3);
        zl[ 1][tid] = make_float4(z4,  z5,  z6,  z7);
        zl[ 2][tid] = make_float4(z8,  z9,  z10, z11);
        zl[ 3][tid] = make_float4(z12, z13, z14, z15);
        zl[ 4][tid] = make_float4(z16, z17, z18, z19);
        zl[ 5][tid] = make_float4(z20, z21, z22, z23);
        zl[ 6][tid] = make_float4(z24, z25, z26, z27);
        zl[ 7][tid] = make_float4(z28, z29, z30, z31);
        zl[ 8][tid] = make_float4(z32, z33, z34, z35);
        zl[ 9][tid] = make_float4(z36, z37, z38, z39);
        zl[10][tid] = make_float4(z40, z41, z42, z43);
        zl[11][tid] = make_float4(z44, z45, z46, z47);
        zl[12][tid] = make_float4(z48, z49, z50, z51);
        zl[13][tid] = make_float4(z52, z53, z54, z55);
        zl[14][tid] = make_float4(z56, z57, z58, z59);
        zl[15][tid] = make_float4(z60, z61, z62, z63);
    }

    // --- my two codes' w into registers (one-time; 32 x float4) ---
    const int cbase = wid * 128;                      // wave's code base
    float4 wa[16], wb[16];
    {
        const float4* wpa = (const float4*)(cb + ((size_t)(cbase + lane)      << 6));
        const float4* wpb = (const float4*)(cb + ((size_t)(cbase + lane + 64) << 6));
#pragma unroll
        for (int kk = 0; kk < 16; ++kk) { wa[kk] = wpa[kk]; wb[kk] = wpb[kk]; }
    }
    WSQ_OF(wa, wsqA)
    WSQ_OF(wb, wsqB)
    __syncthreads();

    // --- row loop: 8 rows/iter, 16 indep FMA chains, 8 shfl chains ---
#pragma unroll 1
    for (int r = 0; r < 256; r += 8) {
        float aA0 = 0.f, aA1 = 0.f, aA2 = 0.f, aA3 = 0.f;
        float aA4 = 0.f, aA5 = 0.f, aA6 = 0.f, aA7 = 0.f;
        float aB0 = 0.f, aB1 = 0.f, aB2 = 0.f, aB3 = 0.f;
        float aB4 = 0.f, aB5 = 0.f, aB6 = 0.f, aB7 = 0.f;
#pragma unroll
        for (int kk = 0; kk < 16; ++kk) {
            const float4 zc0 = zl[kk][r + 0];   // broadcast reads
            const float4 zc1 = zl[kk][r + 1];
            const float4 zc2 = zl[kk][r + 2];
            const float4 zc3 = zl[kk][r + 3];
            const float4 zc4 = zl[kk][r + 4];
            const float4 zc5 = zl[kk][r + 5];
            const float4 zc6 = zl[kk][r + 6];
            const float4 zc7 = zl[kk][r + 7];
            const float4 WA = wa[kk];
            const float4 WB = wb[kk];
            FM4(aA0, zc0, WA) FM4(aA1, zc1, WA) FM4(aA2, zc2, WA) FM4(aA3, zc3, WA)
            FM4(aA4, zc4, WA) FM4(aA5, zc5, WA) FM4(aA6, zc6, WA) FM4(aA7, zc7, WA)
            FM4(aB0, zc0, WB) FM4(aB1, zc1, WB) FM4(aB2, zc2, WB) FM4(aB3, zc3, WB)
            FM4(aB4, zc4, WB) FM4(aB5, zc5, WB) FM4(aB6, zc6, WB) FM4(aB7, zc7, WB)
        }
        // d = (zsq - 2*dot) + wsq, each op individually rounded
#define DISTP(j) \
        const float zr##j = zsql[r + j]; \
        const float dA##j = __fadd_rn(__fsub_rn(zr##j, __fmul_rn(2.0f, aA##j)), wsqA); \
        const float dB##j = __fadd_rn(__fsub_rn(zr##j, __fmul_rn(2.0f, aB##j)), wsqB); \
        const bool tB##j = (dB##j < dA##j); \
        const float d##j = tB##j ? dB##j : dA##j;
        DISTP(0) DISTP(1) DISTP(2) DISTP(3)
        DISTP(4) DISTP(5) DISTP(6) DISTP(7)
#undef DISTP
        // 8 independent wave-min chains, interleaved -> pipelined bpermutes
        float m0 = d0, m1 = d1, m2 = d2, m3 = d3;
        float m4 = d4, m5 = d5, m6 = d6, m7 = d7;
#pragma unroll
        for (int off = 32; off > 0; off >>= 1) {
            m0 = fminf(m0, __shfl_xor(m0, off, 64));
            m1 = fminf(m1, __shfl_xor(m1, off, 64));
            m2 = fminf(m2, __shfl_xor(m2, off, 64));
            m3 = fminf(m3, __shfl_xor(m3, off, 64));
            m4 = fminf(m4, __shfl_xor(m4, off, 64));
            m5 = fminf(m5, __shfl_xor(m5, off, 64));
            m6 = fminf(m6, __shfl_xor(m6, off, 64));
            m7 = fminf(m7, __shfl_xor(m7, off, 64));
        }
        // first-min index per row: A-class codes < B-class; lane order ==
        // code order within a class -> lowest set lane wins.
#define ARGMIN_J(j) { \
        const unsigned long long mskA = __ballot((!tB##j) && (d##j == m##j)); \
        const unsigned long long mskB = __ballot(tB##j && (d##j == m##j)); \
        int code; \
        if (mskA) code = cbase + (__ffsll((long long)mskA) - 1); \
        else      code = cbase + 64 + (__ffsll((long long)mskB) - 1); \
        if (lane == 0) res[wid][r + j] = make_float2(m##j, (float)code); }
        ARGMIN_J(0) ARGMIN_J(1) ARGMIN_J(2) ARGMIN_J(3)
        ARGMIN_J(4) ARGMIN_J(5) ARGMIN_J(6) ARGMIN_J(7)
#undef ARGMIN_J
    }
    __syncthreads();

    // --- combine 8 waves (ascending wid == ascending code blocks) ---
    if (tid < 256) {
        float2 best = res[0][tid];
#pragma unroll
        for (int w = 1; w < 8; ++w) {
            const float2 p = res[w][tid];
            if (p.x < best.x) best = p;   // strict < keeps lower codes
        }
        codes[row0 + tid] = best.y;
        codesl[tid] = (int)best.y;
    }
    __syncthreads();

    // --- fused epilogue: thread (q=tid>>8, row=tid&255) owns 8 float4
    //     chunks of one row. zl b128 reads at 16B lane stride = conflict-
    //     free; coalesced stores per d-plane. out = fl(z + fl(w - z)). ---
    const int q   = tid >> 8;                         // 0..1
    const int row = tid & 255;
    const int code = codesl[row];
    double lsum = 0.0;
    float* outb = out + (size_t)b * (D_DIM * T_DIM) + t0 + row;
#pragma unroll
    for (int j = 0; j < 8; ++j) {
        const int it = q * 8 + j;
        const float4 z4 = zl[it][row];
        const float4 w4 = *(const float4*)(cb + ((size_t)code << 6) + (it << 2));
        const float df0 = __fsub_rn(w4.x, z4.x);
        const float df1 = __fsub_rn(w4.y, z4.y);
        const float df2 = __fsub_rn(w4.z, z4.z);
        const float df3 = __fsub_rn(w4.w, z4.w);
        outb[(size_t)((it << 2) + 0) * T_DIM] = __fadd_rn(z4.x, df0);
        outb[(size_t)((it << 2) + 1) * T_DIM] = __fadd_rn(z4.y, df1);
        outb[(size_t)((it << 2) + 2) * T_DIM] = __fadd_rn(z4.z, df2);
        outb[(size_t)((it << 2) + 3) * T_DIM] = __fadd_rn(z4.w, df3);
        lsum += (double)df0 * df0 + (double)df1 * df1
              + (double)df2 * df2 + (double)df3 * df3;
    }
    // wave reduce (double) then block reduce via LDS
#pragma unroll
    for (int o2 = 32; o2 > 0; o2 >>= 1) lsum += __shfl_down(lsum, o2, 64);
    __shared__ double redd[8];
    if (lane == 0) redd[wid] = lsum;
    __syncthreads();
    if (tid == 0) {
        partials[blockIdx.x] = ((redd[0] + redd[1]) + (redd[2] + redd[3]))
                             + ((redd[4] + redd[5]) + (redd[6] + redd[7]));
    }
}

__global__ void vq_loss_kernel(const double* __restrict__ partials,
                               float* __restrict__ out_loss) {
    double s = 0.0;
    for (int i = threadIdx.x; i < NBLKS; i += 256) s += partials[i];
#pragma unroll
    for (int o = 32; o > 0; o >>= 1) s += __shfl_down(s, o, 64);
    __shared__ double red[4];
    if ((threadIdx.x & 63) == 0) red[threadIdx.x >> 6] = s;
    __syncthreads();
    if (threadIdx.x == 0) {
        double tot = (red[0] + red[1]) + (red[2] + red[3]);
        // vq_loss = codebook_loss + 0.25*commitment_loss = 1.25*mean(diff^2)
        out_loss[0] = (float)(1.25 * tot / (double)NELEM);
    }
}

extern "C" void kernel_launch(void* const* d_in, const int* in_sizes, int n_in,
                              void* d_out, int out_size, void* d_ws, size_t ws_size,
                              hipStream_t stream) {
    const float* z  = (const float*)d_in[0];   // 4194304
    const float* cb = (const float*)d_in[1];   // 65536

    float* out      = (float*)d_out;
    float* out_loss = out + NELEM;             // index 4194304
    float* codes    = out + NELEM + 1;         // 65536 floats

    double* partials = (double*)d_ws;          // 2 KiB (256 doubles)

    vq_fused_kernel<<<NBLKS, 512, 0, stream>>>(z, cb, out, codes, partials);
    vq_loss_kernel<<<1, 256, 0, stream>>>(partials, out_loss);
}